// Round 1
// baseline (4873.724 us; speedup 1.0000x reference)
//
#include <hip/hip_runtime.h>
#include <math.h>

#define N_NODES   150000
#define N_EDGES   1500000
#define N_GRAPHS  150
#define HID       100
#define BATCH     30
#define SEQ       5

// ---------------- degree / norm ----------------
__global__ void k_deg_init(float* deg) {
    int i = blockIdx.x * blockDim.x + threadIdx.x;
    if (i < N_NODES) deg[i] = 1.0f;   // self loop
}

__global__ void k_deg_count(const int* __restrict__ dst, float* deg) {
    int e = blockIdx.x * blockDim.x + threadIdx.x;
    if (e < N_EDGES) atomicAdd(&deg[dst[e]], 1.0f);
}

__global__ void k_dinv(float* deg) {
    int i = blockIdx.x * blockDim.x + threadIdx.x;
    if (i < N_NODES) deg[i] = 1.0f / sqrtf(deg[i]);
}

__global__ void k_norm(const int* __restrict__ src, const int* __restrict__ dst,
                       const float* __restrict__ dinv, float* __restrict__ norm) {
    int e = blockIdx.x * blockDim.x + threadIdx.x;
    if (e < N_EDGES) norm[e] = dinv[src[e]] * dinv[dst[e]];
}

// ---------------- layer-1 feature transform: h1 = x * W1 (IN_F == 1) -------
__global__ void k_h1(const float* __restrict__ x, const float* __restrict__ W1,
                     float* __restrict__ h1) {
    int idx = blockIdx.x * blockDim.x + threadIdx.x;
    if (idx < N_NODES * HID) {
        int n = idx / HID;
        int j = idx - n * HID;
        h1[idx] = x[n] * W1[j];
    }
}

// out[n][j] = h[n][j]*dinv[n]^2 + b[j]   (self-loop term + bias)
__global__ void k_init_out(const float* __restrict__ h, const float* __restrict__ dinv,
                           const float* __restrict__ b, float* __restrict__ out) {
    int idx = blockIdx.x * blockDim.x + threadIdx.x;
    if (idx < N_NODES * HID) {
        int n = idx / HID;
        int j = idx - n * HID;
        float dv = dinv[n];
        out[idx] = h[idx] * dv * dv + b[j];
    }
}

// scatter: out[dst] += h[src] * norm[e]  ; one thread per (edge, 4-feature group)
__global__ void k_scatter(const int* __restrict__ src, const int* __restrict__ dst,
                          const float* __restrict__ norm, const float* __restrict__ h,
                          float* __restrict__ out) {
    int tid = blockIdx.x * blockDim.x + threadIdx.x;
    if (tid >= N_EDGES * 25) return;
    int e = tid / 25;
    int q = tid - e * 25;
    int s = src[e];
    int d = dst[e];
    float nm = norm[e];
    float4 v = reinterpret_cast<const float4*>(h + (size_t)s * HID)[q];
    float* op = out + (size_t)d * HID + q * 4;
    atomicAdd(op + 0, v.x * nm);
    atomicAdd(op + 1, v.y * nm);
    atomicAdd(op + 2, v.z * nm);
    atomicAdd(op + 3, v.w * nm);
}

// ---------------- h2 = A(150000x100) @ W(100x100) ----------------
#define TN 32
__global__ __launch_bounds__(256) void k_gemm(const float* __restrict__ A,
                                              const float* __restrict__ W,
                                              float* __restrict__ C) {
    __shared__ float4 Wl[HID * 25];     // W as [k][j4] float4 : 40 KB
    __shared__ float  At[TN * HID];     // 12.8 KB
    int t = threadIdx.x;
    for (int i = t; i < HID * 25; i += 256)
        Wl[i] = reinterpret_cast<const float4*>(W)[i];
    int n0 = blockIdx.x * TN;
    for (int i = t; i < TN * HID; i += 256) {
        int gidx = n0 * HID + i;
        At[i] = (gidx < N_NODES * HID) ? A[gidx] : 0.0f;
    }
    __syncthreads();
    for (int w = t; w < TN * 25; w += 256) {
        int ln = w / 25;
        int j4 = w - ln * 25;
        if (n0 + ln >= N_NODES) continue;
        float4 acc = make_float4(0.f, 0.f, 0.f, 0.f);
        const float* arow = At + ln * HID;
        for (int k = 0; k < HID; ++k) {
            float a = arow[k];
            float4 wv = Wl[k * 25 + j4];
            acc.x += a * wv.x;
            acc.y += a * wv.y;
            acc.z += a * wv.z;
            acc.w += a * wv.w;
        }
        reinterpret_cast<float4*>(C + (size_t)(n0 + ln) * HID)[j4] = acc;
    }
}

// ---------------- pooling ----------------
__global__ void k_zero(float* p, int n) {
    int i = blockIdx.x * blockDim.x + threadIdx.x;
    if (i < n) p[i] = 0.0f;
}

// grid = N_GRAPHS*10 ; each block sums 100 nodes for all 100 features
__global__ void k_pool(const float* __restrict__ out2, float* __restrict__ pooled) {
    int g = blockIdx.x / 10;
    int chunk = blockIdx.x - g * 10;
    int j = threadIdx.x;
    if (j >= HID) return;
    int base = g * 1000 + chunk * 100;
    float s = 0.0f;
    for (int n = 0; n < 100; ++n)
        s += out2[(size_t)(base + n) * HID + j];
    atomicAdd(&pooled[g * HID + j], s);
}

// ---------------- LSTM (one block per batch element) + output head ---------
__global__ __launch_bounds__(512) void k_lstm(const float* __restrict__ pooled,
                                              const float* __restrict__ W_ih,
                                              const float* __restrict__ W_hh,
                                              const float* __restrict__ b_ih,
                                              const float* __restrict__ b_hh,
                                              const float* __restrict__ W_out,
                                              const float* __restrict__ b_out,
                                              float* __restrict__ outp) {
    int b = blockIdx.x;
    int t = threadIdx.x;
    __shared__ float hs[HID], cs[HID], xs[HID], gs[4 * HID];
    __shared__ float red[512];
    if (t < HID) { hs[t] = 0.0f; cs[t] = 0.0f; }
    __syncthreads();
    for (int step = 0; step < SEQ; ++step) {
        if (t < HID) xs[t] = pooled[(b * SEQ + step) * HID + t] / 1000.0f;
        __syncthreads();
        if (t < 4 * HID) {
            float acc = b_ih[t] + b_hh[t];
            const float* wi = W_ih + t * HID;
            const float* wh = W_hh + t * HID;
            for (int k = 0; k < HID; ++k)
                acc += xs[k] * wi[k] + hs[k] * wh[k];
            gs[t] = acc;
        }
        __syncthreads();
        if (t < HID) {
            float ig = 1.0f / (1.0f + expf(-gs[t]));
            float fg = 1.0f / (1.0f + expf(-gs[HID + t]));
            float gg = tanhf(gs[2 * HID + t]);
            float og = 1.0f / (1.0f + expf(-gs[3 * HID + t]));
            float c  = fg * cs[t] + ig * gg;
            cs[t] = c;
            hs[t] = og * tanhf(c);
        }
        __syncthreads();
    }
    float v = 0.0f;
    if (t < HID) v = hs[t] * W_out[t];
    red[t] = v;
    __syncthreads();
    for (int s = 256; s > 0; s >>= 1) {
        if (t < s) red[t] += red[t + s];
        __syncthreads();
    }
    if (t == 0) outp[b] = red[0] + b_out[0];
}

// ---------------- launch ----------------
extern "C" void kernel_launch(void* const* d_in, const int* in_sizes, int n_in,
                              void* d_out, int out_size, void* d_ws, size_t ws_size,
                              hipStream_t stream) {
    const float* x    = (const float*)d_in[0];
    const int*   ei   = (const int*)d_in[1];
    const int*   srcp = ei;
    const int*   dstp = ei + N_EDGES;
    const float* W1   = (const float*)d_in[3];
    const float* b1   = (const float*)d_in[4];
    const float* W2   = (const float*)d_in[5];
    const float* b2   = (const float*)d_in[6];
    const float* W_ih = (const float*)d_in[7];
    const float* W_hh = (const float*)d_in[8];
    const float* b_ih = (const float*)d_in[9];
    const float* b_hh = (const float*)d_in[10];
    const float* W_out= (const float*)d_in[11];
    const float* b_out= (const float*)d_in[12];
    float* out = (float*)d_out;

    float* ws     = (float*)d_ws;
    float* dinv   = ws;                                  // 150000
    float* norm   = dinv + N_NODES;                      // 1.5M
    float* bufA   = norm + N_EDGES;                      // 15M
    float* bufB   = bufA + (size_t)N_NODES * HID;        // 15M
    float* pooled = bufB + (size_t)N_NODES * HID;        // 15000

    const int B = 256;
    int gN   = (N_NODES + B - 1) / B;
    int gE   = (N_EDGES + B - 1) / B;
    int gNH  = (N_NODES * HID + B - 1) / B;
    int gSC  = (N_EDGES * 25 + B - 1) / B;

    // degree + norm
    k_deg_init<<<gN, B, 0, stream>>>(dinv);
    k_deg_count<<<gE, B, 0, stream>>>(dstp, dinv);
    k_dinv<<<gN, B, 0, stream>>>(dinv);
    k_norm<<<gE, B, 0, stream>>>(srcp, dstp, dinv, norm);

    // GCN layer 1
    k_h1<<<gNH, B, 0, stream>>>(x, W1, bufA);
    k_init_out<<<gNH, B, 0, stream>>>(bufA, dinv, b1, bufB);
    k_scatter<<<gSC, B, 0, stream>>>(srcp, dstp, norm, bufA, bufB);

    // GCN layer 2
    k_gemm<<<(N_NODES + TN - 1) / TN, 256, 0, stream>>>(bufB, W2, bufA);
    k_init_out<<<gNH, B, 0, stream>>>(bufA, dinv, b2, bufB);
    k_scatter<<<gSC, B, 0, stream>>>(srcp, dstp, norm, bufA, bufB);

    // pool
    k_zero<<<(N_GRAPHS * HID + B - 1) / B, B, 0, stream>>>(pooled, N_GRAPHS * HID);
    k_pool<<<N_GRAPHS * 10, 128, 0, stream>>>(bufB, pooled);

    // LSTM + head
    k_lstm<<<BATCH, 512, 0, stream>>>(pooled, W_ih, W_hh, b_ih, b_hh, W_out, b_out, out);
}

// Round 2
// 370.150 us; speedup vs baseline: 13.1669x; 13.1669x over previous
//
#include <hip/hip_runtime.h>
#include <math.h>

#define N_NODES   150000
#define N_EDGES   1500000
#define N_GRAPHS  150
#define HID       100
#define BATCH     30
#define SEQ       5
#define NODES_PER_GRAPH 1000

// ---------------- degree ----------------
__global__ void k_deg_init(float* deg) {
    int i = blockIdx.x * blockDim.x + threadIdx.x;
    if (i < N_NODES) deg[i] = 1.0f;   // self loop
}

__global__ void k_deg_count(const int* __restrict__ dst, float* deg) {
    int e = blockIdx.x * blockDim.x + threadIdx.x;
    if (e < N_EDGES) atomicAdd(&deg[dst[e]], 1.0f);
}

// dinv + init of layer-1 scalar aggregate and weight-sum (self-loop terms)
__global__ void k_node_init(const float* __restrict__ deg, const float* __restrict__ x,
                            float* __restrict__ dinv, float* __restrict__ agg1,
                            float* __restrict__ wsum) {
    int i = blockIdx.x * blockDim.x + threadIdx.x;
    if (i < N_NODES) {
        float dv = 1.0f / sqrtf(deg[i]);
        float dv2 = dv * dv;
        dinv[i] = dv;
        agg1[i] = x[i] * dv2;   // dinv^2 * x[n]  (self loop)
        wsum[i] = dv2;          // dinv^2 * 1     (self loop)
    }
}

// edge pass 1: agg1[d] += w * x[s];  wsum[d] += w
__global__ void k_edge1(const int* __restrict__ src, const int* __restrict__ dst,
                        const float* __restrict__ dinv, const float* __restrict__ x,
                        float* __restrict__ agg1, float* __restrict__ wsum) {
    int e = blockIdx.x * blockDim.x + threadIdx.x;
    if (e < N_EDGES) {
        int s = src[e], d = dst[e];
        float w = dinv[s] * dinv[d];
        atomicAdd(&agg1[d], x[s] * w);
        atomicAdd(&wsum[d], w);
    }
}

__global__ void k_agg2_init(const float* __restrict__ agg1, const float* __restrict__ dinv,
                            float* __restrict__ agg2) {
    int i = blockIdx.x * blockDim.x + threadIdx.x;
    if (i < N_NODES) {
        float dv = dinv[i];
        agg2[i] = agg1[i] * dv * dv;
    }
}

// edge pass 2: agg2[d] += w * agg1[s]
__global__ void k_edge2(const int* __restrict__ src, const int* __restrict__ dst,
                        const float* __restrict__ dinv, const float* __restrict__ agg1,
                        float* __restrict__ agg2) {
    int e = blockIdx.x * blockDim.x + threadIdx.x;
    if (e < N_EDGES) {
        int s = src[e], d = dst[e];
        float w = dinv[s] * dinv[d];
        atomicAdd(&agg2[d], agg1[s] * w);
    }
}

// ---------------- fused tail: v1/v2, per-graph means, LSTM, head -----------
// out2[n][j] = agg2[n]*v1[j] + wsum[n]*v2[j] + b2[j]
// pooled[g][j] = mean_a[g]*v1[j] + mean_w[g]*v2[j] + b2[j]
// v1 = W1^T W2, v2 = b1^T W2
__global__ __launch_bounds__(512) void k_tail(const float* __restrict__ agg2,
                                              const float* __restrict__ wsum,
                                              const float* __restrict__ W1,
                                              const float* __restrict__ b1,
                                              const float* __restrict__ W2,
                                              const float* __restrict__ b2,
                                              const float* __restrict__ W_ih,
                                              const float* __restrict__ W_hh,
                                              const float* __restrict__ b_ih,
                                              const float* __restrict__ b_hh,
                                              const float* __restrict__ W_out,
                                              const float* __restrict__ b_out,
                                              float* __restrict__ outp) {
    int b = blockIdx.x;
    int t = threadIdx.x;
    __shared__ float v1[HID], v2[HID];
    __shared__ float hs[HID], cs[HID], xs[HID], gs[4 * HID];
    __shared__ float red_a[512], red_w[512];
    __shared__ float mean_a_s, mean_w_s;

    if (t < HID) {
        float a = 0.0f, c = 0.0f;
        for (int k = 0; k < HID; ++k) {
            float w2 = W2[k * HID + t];
            a += W1[k] * w2;
            c += b1[k] * w2;
        }
        v1[t] = a; v2[t] = c;
        hs[t] = 0.0f; cs[t] = 0.0f;
    }
    __syncthreads();

    for (int step = 0; step < SEQ; ++step) {
        int g = b * SEQ + step;
        const float* pa = agg2 + (size_t)g * NODES_PER_GRAPH;
        const float* pw = wsum + (size_t)g * NODES_PER_GRAPH;
        float sa = 0.0f, sw = 0.0f;
        for (int n = t; n < NODES_PER_GRAPH; n += 512) { sa += pa[n]; sw += pw[n]; }
        red_a[t] = sa; red_w[t] = sw;
        __syncthreads();
        for (int s = 256; s > 0; s >>= 1) {
            if (t < s) { red_a[t] += red_a[t + s]; red_w[t] += red_w[t + s]; }
            __syncthreads();
        }
        if (t == 0) {
            mean_a_s = red_a[0] * (1.0f / NODES_PER_GRAPH);
            mean_w_s = red_w[0] * (1.0f / NODES_PER_GRAPH);
        }
        __syncthreads();
        if (t < HID) xs[t] = mean_a_s * v1[t] + mean_w_s * v2[t] + b2[t];
        __syncthreads();
        if (t < 4 * HID) {
            float acc = b_ih[t] + b_hh[t];
            const float* wi = W_ih + t * HID;
            const float* wh = W_hh + t * HID;
            for (int k = 0; k < HID; ++k)
                acc += xs[k] * wi[k] + hs[k] * wh[k];
            gs[t] = acc;
        }
        __syncthreads();
        if (t < HID) {
            float ig = 1.0f / (1.0f + expf(-gs[t]));
            float fg = 1.0f / (1.0f + expf(-gs[HID + t]));
            float gg = tanhf(gs[2 * HID + t]);
            float og = 1.0f / (1.0f + expf(-gs[3 * HID + t]));
            float c  = fg * cs[t] + ig * gg;
            cs[t] = c;
            hs[t] = og * tanhf(c);
        }
        __syncthreads();
    }

    float v = (t < HID) ? hs[t] * W_out[t] : 0.0f;
    red_a[t] = v;
    __syncthreads();
    for (int s = 256; s > 0; s >>= 1) {
        if (t < s) red_a[t] += red_a[t + s];
        __syncthreads();
    }
    if (t == 0) outp[b] = red_a[0] + b_out[0];
}

// ---------------- launch ----------------
extern "C" void kernel_launch(void* const* d_in, const int* in_sizes, int n_in,
                              void* d_out, int out_size, void* d_ws, size_t ws_size,
                              hipStream_t stream) {
    const float* x    = (const float*)d_in[0];
    const int*   ei   = (const int*)d_in[1];
    const int*   srcp = ei;
    const int*   dstp = ei + N_EDGES;
    const float* W1   = (const float*)d_in[3];
    const float* b1   = (const float*)d_in[4];
    const float* W2   = (const float*)d_in[5];
    const float* b2   = (const float*)d_in[6];
    const float* W_ih = (const float*)d_in[7];
    const float* W_hh = (const float*)d_in[8];
    const float* b_ih = (const float*)d_in[9];
    const float* b_hh = (const float*)d_in[10];
    const float* W_out= (const float*)d_in[11];
    const float* b_out= (const float*)d_in[12];
    float* out = (float*)d_out;

    float* ws   = (float*)d_ws;
    float* deg  = ws;                 // 150000
    float* dinv = deg  + N_NODES;     // 150000
    float* agg1 = dinv + N_NODES;     // 150000
    float* wsum = agg1 + N_NODES;     // 150000
    float* agg2 = wsum + N_NODES;     // 150000

    const int B = 256;
    int gN = (N_NODES + B - 1) / B;
    int gE = (N_EDGES + B - 1) / B;

    k_deg_init<<<gN, B, 0, stream>>>(deg);
    k_deg_count<<<gE, B, 0, stream>>>(dstp, deg);
    k_node_init<<<gN, B, 0, stream>>>(deg, x, dinv, agg1, wsum);
    k_edge1<<<gE, B, 0, stream>>>(srcp, dstp, dinv, x, agg1, wsum);
    k_agg2_init<<<gN, B, 0, stream>>>(agg1, dinv, agg2);
    k_edge2<<<gE, B, 0, stream>>>(srcp, dstp, dinv, agg1, agg2);
    k_tail<<<BATCH, 512, 0, stream>>>(agg2, wsum, W1, b1, W2, b2,
                                      W_ih, W_hh, b_ih, b_hh, W_out, b_out, out);
}